// Round 2
// baseline (320.833 us; speedup 1.0000x reference)
//
#include <hip/hip_runtime.h>
#include <hip/hip_bf16.h>

typedef __attribute__((ext_vector_type(8))) short bf16x8;   // 8 bf16 = 4 VGPR (MFMA A/B frag)
typedef __attribute__((ext_vector_type(4))) float f32x4;    // MFMA C/D frag
typedef __attribute__((ext_vector_type(2))) float f32x2;

// may_alias variants: ALL LDS traffic goes through these so TBAA can never
// prove a staging/init store dead (R1 post-timing divergence root cause:
// the u16 zero-init stores were DSE'd -> replays read stale LDS from the
// previous launch; launch 1 read lucky zeros).
typedef bf16x8 bf16x8_a __attribute__((may_alias));
typedef f32x2  f32x2_a  __attribute__((may_alias));
typedef unsigned short u16a __attribute__((may_alias));

#if __has_builtin(__builtin_amdgcn_exp2f)
#define EXP2(x) __builtin_amdgcn_exp2f(x)
#else
#define EXP2(x) exp2f(x)
#endif
#if __has_builtin(__builtin_amdgcn_rcpf)
#define RCP(x) __builtin_amdgcn_rcpf(x)
#else
#define RCP(x) (1.0f / (x))
#endif

// LDS layout (bytes). Weight tiles bf16 [n][k] row-major with XOR swizzle
// kbyte ^= (n&7)<<4 so stride-128/256B ds_read_b128 is bank-balanced.
#define LDS_WRZ   0        // [128][128] bf16: rows 0..127 of (w_ih | w_hh) (r,z), 32 KB
#define LDS_WIN   32768    // [64][64] bf16: w_ih rows 128..191 (i_n)
#define LDS_WHN   40960    // [64][64] bf16: w_hh rows 128..191 (h_n)
#define LDS_WOUT  49152    // [64][64] bf16: w_out
#define LDS_X     57344    // [16 rows][128 k] bf16: X = [s | h], swizzled
#define LDS_SIZE  61440

__device__ __forceinline__ void stbf(char* smem, int byteoff, float v) {
  union { __hip_bfloat16 b; unsigned short u; } cv;
  cv.b = __float2bfloat16(v);
  *(u16a*)(smem + byteoff) = cv.u;
}

// Intra-wave LDS RAW fence: LDS writes complete before any later ds_read
// issues. Single wave -> no s_barrier needed; lgkm-only (does NOT drain
// vmcnt, so global out-stores stay fire-and-forget).
__device__ __forceinline__ void lds_fence() {
  asm volatile("s_waitcnt lgkmcnt(0)" ::: "memory");
}

// grid: 4096/16 = 256 blocks, 64 threads (ONE wave)
__global__ __launch_bounds__(64, 1)
void gru_fused(const float* __restrict__ s0, const float* __restrict__ a,
               const float* __restrict__ w_ih, const float* __restrict__ w_hh,
               const float* __restrict__ b_ih, const float* __restrict__ b_hh,
               const float* __restrict__ w_out, const float* __restrict__ b_out,
               float* __restrict__ out)
{
  __shared__ __align__(16) char smem[LDS_SIZE];
  const int l = threadIdx.x;
  const int c = l & 15;        // MFMA col lane / A-row lane
  const int g = l >> 4;        // k-block / C-row group
  const int b0 = blockIdx.x * 16;

  // ---- stage weights -> LDS bf16, swizzled ----
  for (int idx = l; idx < 128 * 128; idx += 64) {
    int n = idx >> 7, k = idx & 127;
    float w = (k < 64) ? w_ih[n * 66 + k] : w_hh[n * 64 + (k - 64)];
    stbf(smem, LDS_WRZ + n * 256 + ((k * 2) ^ ((n & 7) << 4)), w);
  }
  for (int idx = l; idx < 64 * 64; idx += 64) {
    int n = idx >> 6, k = idx & 63;
    int off = n * 128 + ((k * 2) ^ ((n & 7) << 4));
    stbf(smem, LDS_WIN  + off, w_ih[(128 + n) * 66 + k]);
    stbf(smem, LDS_WHN  + off, w_hh[(128 + n) * 64 + k]);
    stbf(smem, LDS_WOUT + off, w_out[n * 64 + k]);
  }
  // ---- X init: s = s0, h = 0 (h-zero now via stbf -> same aliasing class) ----
  for (int idx = l; idx < 16 * 64; idx += 64) {
    int r = idx >> 6, k = idx & 63;
    stbf(smem, LDS_X + r * 256 + ((k * 2) ^ ((r & 7) << 4)), s0[(b0 + r) * 64 + k]);
    stbf(smem, LDS_X + r * 256 + (((64 + k) * 2) ^ ((r & 7) << 4)), 0.0f);
  }

  // ---- per-lane constants (biases folded into MFMA C-init; W_a = w_ih[:,64:66]) ----
  float bias_rz[8], wa0_rz[8], wa1_rz[8];
  #pragma unroll
  for (int i = 0; i < 8; ++i) {
    int n = c + 16 * i;
    bias_rz[i] = b_ih[n] + b_hh[n];
    wa0_rz[i] = w_ih[n * 66 + 64];
    wa1_rz[i] = w_ih[n * 66 + 65];
  }
  float bias_in[4], wa0_in[4], wa1_in[4], bias_hn[4], bias_out[4];
  #pragma unroll
  for (int i = 0; i < 4; ++i) {
    int n = 128 + c + 16 * i;
    bias_in[i] = b_ih[n];
    wa0_in[i] = w_ih[n * 66 + 64];
    wa1_in[i] = w_ih[n * 66 + 65];
    bias_hn[i] = b_hh[n];
    bias_out[i] = b_out[c + 16 * i];
  }
  lds_fence();   // staging visible before first reads

  const int swzc = (c & 7) << 4;     // row%8 == c%8 for all A/B reads
  f32x4 hreg[4];
  #pragma unroll
  for (int i = 0; i < 4; ++i) hreg[i] = f32x4{0.f, 0.f, 0.f, 0.f};

  #pragma unroll 1
  for (int t = 0; t < 128; ++t) {
    // A-frags of X = [s | h]. lane: row=c, k = ks*32 + g*8 + j
    bf16x8 xa[4];
    #pragma unroll
    for (int ks = 0; ks < 4; ++ks)
      xa[ks] = *(const bf16x8_a*)(smem + LDS_X + c * 256 + ((ks * 64 + g * 16) ^ swzc));

    // a_t for this lane's 4 C-rows (rows 4g..4g+3)
    float a0v[4], a1v[4];
    #pragma unroll
    for (int j = 0; j < 4; ++j) {
      f32x2 av = *(const f32x2_a*)(a + (size_t)(b0 + 4 * g + j) * 256 + 2 * t);
      a0v[j] = av.x;
      a1v[j] = av.y;
    }

    // accumulators start at the (replicated) biases
    f32x4 arz[8], ain[4], ahn[4];
    #pragma unroll
    for (int i = 0; i < 8; ++i) arz[i] = f32x4{bias_rz[i], bias_rz[i], bias_rz[i], bias_rz[i]};
    #pragma unroll
    for (int i = 0; i < 4; ++i) {
      ain[i] = f32x4{bias_in[i], bias_in[i], bias_in[i], bias_in[i]};
      ahn[i] = f32x4{bias_hn[i], bias_hn[i], bias_hn[i], bias_hn[i]};
    }

    // GEMM rz: [16,128]x[128,128]  (i_r+h_r, i_z+h_z fused over X=[s|h])
    #pragma unroll
    for (int i = 0; i < 8; ++i) {
      const char* wb = smem + LDS_WRZ + (16 * i + c) * 256;
      #pragma unroll
      for (int ks = 0; ks < 4; ++ks) {
        bf16x8 bw = *(const bf16x8_a*)(wb + ((ks * 64 + g * 16) ^ swzc));
        arz[i] = __builtin_amdgcn_mfma_f32_16x16x32_bf16(xa[ks], bw, arz[i], 0, 0, 0);
      }
    }
    // GEMM i_n (from s: xa[0..1]) and h_n (from h: xa[2..3])
    #pragma unroll
    for (int i = 0; i < 4; ++i) {
      const char* wbi = smem + LDS_WIN + (16 * i + c) * 128;
      const char* wbh = smem + LDS_WHN + (16 * i + c) * 128;
      #pragma unroll
      for (int ks = 0; ks < 2; ++ks) {
        int ko = (ks * 64 + g * 16) ^ swzc;
        bf16x8 bwi = *(const bf16x8_a*)(wbi + ko);
        ain[i] = __builtin_amdgcn_mfma_f32_16x16x32_bf16(xa[ks], bwi, ain[i], 0, 0, 0);
        bf16x8 bwh = *(const bf16x8_a*)(wbh + ko);
        ahn[i] = __builtin_amdgcn_mfma_f32_16x16x32_bf16(xa[2 + ks], bwh, ahn[i], 0, 0, 0);
      }
    }

    // ---- gates (C-layout: lane holds rows 4g+j, col c+16i) ----
    f32x4 rg[4];
    #pragma unroll
    for (int i = 0; i < 4; ++i) {
      #pragma unroll
      for (int j = 0; j < 4; ++j) {
        float p = arz[i][j] + a0v[j] * wa0_rz[i] + a1v[j] * wa1_rz[i];
        rg[i][j] = RCP(1.f + EXP2(p * -1.44269504f));                 // sigmoid
      }
    }
    f32x4 hnew[4];
    #pragma unroll
    for (int i = 0; i < 4; ++i) {
      #pragma unroll
      for (int j = 0; j < 4; ++j) {
        float pz = arz[4 + i][j] + a0v[j] * wa0_rz[4 + i] + a1v[j] * wa1_rz[4 + i];
        float z  = RCP(1.f + EXP2(pz * -1.44269504f));                // sigmoid
        float in_ = ain[i][j] + a0v[j] * wa0_in[i] + a1v[j] * wa1_in[i];
        float q  = in_ + rg[i][j] * ahn[i][j];
        float nn = 1.f - 2.f * RCP(1.f + EXP2(q * 2.88539008f));      // tanh
        hnew[i][j] = nn + z * (hreg[i][j] - nn);
        hreg[i][j] = hnew[i][j];
      }
    }

    // write h_new (bf16) into X h-part
    #pragma unroll
    for (int i = 0; i < 4; ++i) {
      #pragma unroll
      for (int j = 0; j < 4; ++j) {
        int row = 4 * g + j;
        stbf(smem, LDS_X + row * 256 + (((64 + c + 16 * i) * 2) ^ ((row & 7) << 4)), hnew[i][j]);
      }
    }
    lds_fence();   // h writes visible to ha reads (intra-wave, lgkm only)

    // GEMM2: s_new = h_new @ w_out^T  ([16,64]x[64,64])
    bf16x8 ha[2];
    #pragma unroll
    for (int ks = 0; ks < 2; ++ks)
      ha[ks] = *(const bf16x8_a*)(smem + LDS_X + c * 256 + (((2 + ks) * 64 + g * 16) ^ swzc));
    f32x4 as_[4];
    #pragma unroll
    for (int i = 0; i < 4; ++i) as_[i] = f32x4{bias_out[i], bias_out[i], bias_out[i], bias_out[i]};
    #pragma unroll
    for (int i = 0; i < 4; ++i) {
      const char* wb = smem + LDS_WOUT + (16 * i + c) * 128;
      #pragma unroll
      for (int ks = 0; ks < 2; ++ks) {
        bf16x8 bw = *(const bf16x8_a*)(wb + ((ks * 64 + g * 16) ^ swzc));
        as_[i] = __builtin_amdgcn_mfma_f32_16x16x32_bf16(ha[ks], bw, as_[i], 0, 0, 0);
      }
    }

    // write s_new: bf16 into X s-part + f32 to global out (async, never drained)
    #pragma unroll
    for (int i = 0; i < 4; ++i) {
      #pragma unroll
      for (int j = 0; j < 4; ++j) {
        float sv = as_[i][j];
        int row = 4 * g + j;
        stbf(smem, LDS_X + row * 256 + (((c + 16 * i) * 2) ^ ((row & 7) << 4)), sv);
        out[((size_t)(b0 + row) * 128 + t) * 64 + (c + 16 * i)] = sv;
      }
    }
    lds_fence();   // s/h state visible to next iteration's xa reads
  }
}

extern "C" void kernel_launch(void* const* d_in, const int* in_sizes, int n_in,
                              void* d_out, int out_size, void* d_ws, size_t ws_size,
                              hipStream_t stream) {
  const float* s0    = (const float*)d_in[0];
  const float* a     = (const float*)d_in[1];
  const float* w_ih  = (const float*)d_in[2];
  const float* w_hh  = (const float*)d_in[3];
  const float* b_ih  = (const float*)d_in[4];
  const float* b_hh  = (const float*)d_in[5];
  const float* w_out = (const float*)d_in[6];
  const float* b_out = (const float*)d_in[7];
  float* out = (float*)d_out;
  hipLaunchKernelGGL(gru_fused, dim3(4096 / 16), dim3(64), 0, stream,
                     s0, a, w_ih, w_hh, b_ih, b_hh, w_out, b_out, out);
}

// Round 3
// 91.121 us; speedup vs baseline: 3.5210x; 3.5210x over previous
//
#include <hip/hip_runtime.h>
#include <hip/hip_bf16.h>

typedef __attribute__((ext_vector_type(8))) short bf16x8;   // MFMA A/B frag (4 VGPR)
typedef __attribute__((ext_vector_type(4))) float f32x4;    // MFMA C/D frag
typedef __attribute__((ext_vector_type(2))) float f32x2;

// may_alias everywhere for LDS + vector global loads (R1 lesson: TBAA DSE'd
// init stores -> stale-LDS divergence on graph replays).
typedef bf16x8 bf16x8_a __attribute__((may_alias));
typedef f32x4  f32x4_a  __attribute__((may_alias));
typedef f32x2  f32x2_a  __attribute__((may_alias));
typedef unsigned short u16a __attribute__((may_alias));

#if __has_builtin(__builtin_amdgcn_rcpf)
#define RCP(x) __builtin_amdgcn_rcpf(x)
#else
#define RCP(x) (1.0f / (x))
#endif
#define EXP2(x) exp2f(x)

// LDS: WG = combined weight matrix [192][64] bf16 (rows 0..127: W_s@w_out + W_hh
// for r,z; rows 128..191: W_s@w_out for i_n), swizzled rows of 128 B.
// HB = double-buffered h state [2][16 rows][64 hh] bf16, swizzled.
#define LDS_WG   0        // 192 * 128 = 24576
#define LDS_HB   24576    // 2 * 16 * 128 = 4096
#define LDS_SIZE 28672

__device__ __forceinline__ void stbf(char* smem, int byteoff, float v) {
  union { __hip_bfloat16 b; unsigned short u; } cv;
  cv.b = __float2bfloat16(v);
  *(u16a*)(smem + byteoff) = cv.u;
}

__device__ __forceinline__ bf16x8 packf8(const float* v) {
  bf16x8 r;
  #pragma unroll
  for (int j = 0; j < 8; ++j) {
    union { __hip_bfloat16 b; short u; } cv;
    cv.b = __float2bfloat16(v[j]);
    r[j] = cv.u;
  }
  return r;
}

__device__ __forceinline__ float sigf(float x) {
  return RCP(1.f + EXP2(x * -1.44269504f));
}
__device__ __forceinline__ float tanhf_(float x) {
  return 1.f - 2.f * RCP(1.f + EXP2(x * 2.88539008f));
}

// Cross-wave barrier with LDS-only drain: raw s_barrier, lgkmcnt(0) before it.
// Never drains vmcnt -> global out-stores and a-prefetch stay in flight.
__device__ __forceinline__ void xbar() {
  asm volatile("s_waitcnt lgkmcnt(0)\n\ts_barrier" ::: "memory");
}

// grid: 256 blocks x 256 threads (4 waves). Block owns 16 batch rows; wave w
// owns hidden/gate column chunk [16w, 16w+16).
__global__ __launch_bounds__(256, 1)
void gru_fused(const float* __restrict__ s0, const float* __restrict__ a,
               const float* __restrict__ w_ih, const float* __restrict__ w_hh,
               const float* __restrict__ b_ih, const float* __restrict__ b_hh,
               const float* __restrict__ w_out, const float* __restrict__ b_out,
               float* __restrict__ out)
{
  __shared__ __align__(16) char smem[LDS_SIZE];
  const int tid = threadIdx.x;
  const int l = tid & 63;
  const int w = tid >> 6;          // wave id 0..3
  const int c = l & 15;            // MFMA col/row lane
  const int g = l >> 4;            // k-group 0..3
  const int b0 = blockIdx.x * 16;
  const int swzc = (c & 7) << 4;

  // ---- stage s0 -> hbuf[0] (A-frag source for the peeled t=0 step) ----
  for (int idx = tid; idx < 16 * 64; idx += 256) {
    int r = idx >> 6, k = idx & 63;
    stbf(smem, LDS_HB + r * 128 + ((k * 2) ^ ((r & 7) << 4)), s0[(b0 + r) * 64 + k]);
  }

  // ---- prologue: WG = W_s @ w_out (+ W_hh for rows<128), f32-accum MFMA ----
  // B-frags of w_out: B[k=dd][col=hh=c+16i] = w_out[dd*64 + c+16i]
  bf16x8 bwo[4][2];
  #pragma unroll
  for (int i = 0; i < 4; ++i) {
    #pragma unroll
    for (int ks = 0; ks < 2; ++ks) {
      float tv[8];
      #pragma unroll
      for (int j = 0; j < 8; ++j)
        tv[j] = w_out[(ks * 32 + g * 8 + j) * 64 + c + 16 * i];
      bwo[i][ks] = packf8(tv);
    }
  }
  #pragma unroll
  for (int rr = 0; rr < 3; ++rr) {
    int rt = w + 4 * rr;                       // row-tiles 0..11 (n = 16rt..16rt+15)
    bf16x8 wsa[2];                             // A-frag: W_s row 16rt+c, k=dd
    #pragma unroll
    for (int ks = 0; ks < 2; ++ks) {
      float tv[8];
      #pragma unroll
      for (int u = 0; u < 4; ++u) {
        f32x2 t2 = *(const f32x2_a*)(w_ih + (16 * rt + c) * 66 + ks * 32 + g * 8 + 2 * u);
        tv[2 * u] = t2.x; tv[2 * u + 1] = t2.y;
      }
      wsa[ks] = packf8(tv);
    }
    f32x4 acc[4];
    #pragma unroll
    for (int i = 0; i < 4; ++i) {
      #pragma unroll
      for (int j = 0; j < 4; ++j) {
        int n = 16 * rt + 4 * g + j;
        acc[i][j] = (n < 128) ? w_hh[n * 64 + c + 16 * i] : 0.f;
      }
    }
    #pragma unroll
    for (int i = 0; i < 4; ++i)
      #pragma unroll
      for (int ks = 0; ks < 2; ++ks)
        acc[i] = __builtin_amdgcn_mfma_f32_16x16x32_bf16(wsa[ks], bwo[i][ks], acc[i], 0, 0, 0);
    #pragma unroll
    for (int i = 0; i < 4; ++i)
      #pragma unroll
      for (int j = 0; j < 4; ++j) {
        int n = 16 * rt + 4 * g + j;
        stbf(smem, LDS_WG + n * 128 + (((c + 16 * i) * 2) ^ ((n & 7) << 4)), acc[i][j]);
      }
  }

  // ---- per-lane scalars ----
  const int nr = 16 * w + c, nz = 64 + nr, ni = 128 + nr;
  float bs_r = 0.f, bs_z = 0.f, bs_i = 0.f;
  for (int d = 0; d < 64; ++d) {
    float bo = b_out[d];
    bs_r += w_ih[nr * 66 + d] * bo;
    bs_z += w_ih[nz * 66 + d] * bo;
    bs_i += w_ih[ni * 66 + d] * bo;
  }
  const float wa0_r = w_ih[nr * 66 + 64], wa1_r = w_ih[nr * 66 + 65];
  const float wa0_z = w_ih[nz * 66 + 64], wa1_z = w_ih[nz * 66 + 65];
  const float wa0_i = w_ih[ni * 66 + 64], wa1_i = w_ih[ni * 66 + 65];
  const float pb_r = b_ih[nr] + b_hh[nr];          // peel biases (no b_s)
  const float pb_z = b_ih[nz] + b_hh[nz];
  const float pb_i = b_ih[ni];
  const float bias_r = pb_r + bs_r;                // folded biases (with b_s)
  const float bias_z = pb_z + bs_z;
  const float bias_i = pb_i + bs_i;
  const float bias_hn = b_hh[ni];
  const float bias_o = b_out[nr];

  // ---- register B-frags straight from global (row-major row slices) ----
  bf16x8 whn[2], wo[2], wsr[2], wsz[2], wsi[2];
  #pragma unroll
  for (int ks = 0; ks < 2; ++ks) {
    float tv[8];
    f32x4 t4;
    t4 = *(const f32x4_a*)(w_hh + ni * 64 + ks * 32 + g * 8);
    tv[0] = t4.x; tv[1] = t4.y; tv[2] = t4.z; tv[3] = t4.w;
    t4 = *(const f32x4_a*)(w_hh + ni * 64 + ks * 32 + g * 8 + 4);
    tv[4] = t4.x; tv[5] = t4.y; tv[6] = t4.z; tv[7] = t4.w;
    whn[ks] = packf8(tv);
    t4 = *(const f32x4_a*)(w_out + nr * 64 + ks * 32 + g * 8);
    tv[0] = t4.x; tv[1] = t4.y; tv[2] = t4.z; tv[3] = t4.w;
    t4 = *(const f32x4_a*)(w_out + nr * 64 + ks * 32 + g * 8 + 4);
    tv[4] = t4.x; tv[5] = t4.y; tv[6] = t4.z; tv[7] = t4.w;
    wo[ks] = packf8(tv);
    #pragma unroll
    for (int u = 0; u < 4; ++u) {
      f32x2 t2 = *(const f32x2_a*)(w_ih + nr * 66 + ks * 32 + g * 8 + 2 * u);
      tv[2 * u] = t2.x; tv[2 * u + 1] = t2.y;
    }
    wsr[ks] = packf8(tv);
    #pragma unroll
    for (int u = 0; u < 4; ++u) {
      f32x2 t2 = *(const f32x2_a*)(w_ih + nz * 66 + ks * 32 + g * 8 + 2 * u);
      tv[2 * u] = t2.x; tv[2 * u + 1] = t2.y;
    }
    wsz[ks] = packf8(tv);
    #pragma unroll
    for (int u = 0; u < 4; ++u) {
      f32x2 t2 = *(const f32x2_a*)(w_ih + ni * 66 + ks * 32 + g * 8 + 2 * u);
      tv[2 * u] = t2.x; tv[2 * u + 1] = t2.y;
    }
    wsi[ks] = packf8(tv);
  }

  __syncthreads();   // staging + WG writes visible (full drain OK once)

  // WG B-frags from LDS (combined weights)
  bf16x8 wgr[2], wgz[2], wgi[2];
  #pragma unroll
  for (int ks = 0; ks < 2; ++ks) {
    wgr[ks] = *(const bf16x8_a*)(smem + LDS_WG + nr * 128 + ((ks * 64 + g * 16) ^ swzc));
    wgz[ks] = *(const bf16x8_a*)(smem + LDS_WG + nz * 128 + ((ks * 64 + g * 16) ^ swzc));
    wgi[ks] = *(const bf16x8_a*)(smem + LDS_WG + ni * 128 + ((ks * 64 + g * 16) ^ swzc));
  }

  // ---- peeled t=0: gates from explicit s0 (h0 = 0) ----
  bf16x8 sa[2];
  #pragma unroll
  for (int ks = 0; ks < 2; ++ks)
    sa[ks] = *(const bf16x8_a*)(smem + LDS_HB + c * 128 + ((ks * 64 + g * 16) ^ swzc));
  float a0c[4], a1c[4];
  #pragma unroll
  for (int j = 0; j < 4; ++j) {
    f32x2 av = *(const f32x2_a*)(a + (size_t)(b0 + 4 * g + j) * 256);
    a0c[j] = av.x; a1c[j] = av.y;
  }
  f32x4 ar, az, ai;
  #pragma unroll
  for (int j = 0; j < 4; ++j) {
    ar[j] = pb_r + a0c[j] * wa0_r + a1c[j] * wa1_r;
    az[j] = pb_z + a0c[j] * wa0_z + a1c[j] * wa1_z;
    ai[j] = pb_i + a0c[j] * wa0_i + a1c[j] * wa1_i;
  }
  #pragma unroll
  for (int ks = 0; ks < 2; ++ks) {
    ar = __builtin_amdgcn_mfma_f32_16x16x32_bf16(sa[ks], wsr[ks], ar, 0, 0, 0);
    az = __builtin_amdgcn_mfma_f32_16x16x32_bf16(sa[ks], wsz[ks], az, 0, 0, 0);
    ai = __builtin_amdgcn_mfma_f32_16x16x32_bf16(sa[ks], wsi[ks], ai, 0, 0, 0);
  }
  float hreg[4];
  #pragma unroll
  for (int j = 0; j < 4; ++j) {
    float r = sigf(ar[j]);
    float z = sigf(az[j]);
    float nn = tanhf_(ai[j] + r * bias_hn);
    float h1 = nn - z * nn;                       // h0 = 0
    hreg[j] = h1;
    int row = 4 * g + j;
    stbf(smem, LDS_HB + 2048 + row * 128 + ((2 * nr) ^ ((row & 7) << 4)), h1);
  }
  // prefetch a_1
  f32x2 avn[4];
  #pragma unroll
  for (int j = 0; j < 4; ++j)
    avn[j] = *(const f32x2_a*)(a + (size_t)(b0 + 4 * g + j) * 256 + 2);
  xbar();

  // ---- main loop: iteration t reads h_t, emits out[t-1] and h_{t+1} ----
  #pragma unroll 1
  for (int t = 1; t < 128; ++t) {
    const char* hb = smem + LDS_HB + (t & 1) * 2048 + c * 128;
    bf16x8 ha0 = *(const bf16x8_a*)(hb + ((g * 16) ^ swzc));
    bf16x8 ha1 = *(const bf16x8_a*)(hb + ((64 + g * 16) ^ swzc));

    f32x4 ao = f32x4{bias_o, bias_o, bias_o, bias_o};
    ao = __builtin_amdgcn_mfma_f32_16x16x32_bf16(ha0, wo[0], ao, 0, 0, 0);
    ao = __builtin_amdgcn_mfma_f32_16x16x32_bf16(ha1, wo[1], ao, 0, 0, 0);

    #pragma unroll
    for (int j = 0; j < 4; ++j) { a0c[j] = avn[j].x; a1c[j] = avn[j].y; }
    int tn = (t < 127) ? t + 1 : 127;
    #pragma unroll
    for (int j = 0; j < 4; ++j)
      avn[j] = *(const f32x2_a*)(a + (size_t)(b0 + 4 * g + j) * 256 + 2 * tn);

    f32x4 arr, azz, aii, ahh;
    #pragma unroll
    for (int j = 0; j < 4; ++j) {
      arr[j] = bias_r + a0c[j] * wa0_r + a1c[j] * wa1_r;
      azz[j] = bias_z + a0c[j] * wa0_z + a1c[j] * wa1_z;
      aii[j] = bias_i + a0c[j] * wa0_i + a1c[j] * wa1_i;
      ahh[j] = bias_hn;
    }
    arr = __builtin_amdgcn_mfma_f32_16x16x32_bf16(ha0, wgr[0], arr, 0, 0, 0);
    arr = __builtin_amdgcn_mfma_f32_16x16x32_bf16(ha1, wgr[1], arr, 0, 0, 0);
    azz = __builtin_amdgcn_mfma_f32_16x16x32_bf16(ha0, wgz[0], azz, 0, 0, 0);
    azz = __builtin_amdgcn_mfma_f32_16x16x32_bf16(ha1, wgz[1], azz, 0, 0, 0);
    aii = __builtin_amdgcn_mfma_f32_16x16x32_bf16(ha0, wgi[0], aii, 0, 0, 0);
    aii = __builtin_amdgcn_mfma_f32_16x16x32_bf16(ha1, wgi[1], aii, 0, 0, 0);
    ahh = __builtin_amdgcn_mfma_f32_16x16x32_bf16(ha0, whn[0], ahh, 0, 0, 0);
    ahh = __builtin_amdgcn_mfma_f32_16x16x32_bf16(ha1, whn[1], ahh, 0, 0, 0);

    #pragma unroll
    for (int j = 0; j < 4; ++j) {
      float r = sigf(arr[j]);
      float z = sigf(azz[j]);
      float nn = tanhf_(aii[j] + r * ahh[j]);
      float h = nn + z * (hreg[j] - nn);
      hreg[j] = h;
      int row = 4 * g + j;
      stbf(smem, LDS_HB + ((t + 1) & 1) * 2048 + row * 128 + ((2 * nr) ^ ((row & 7) << 4)), h);
      out[((size_t)(b0 + row) * 128 + (t - 1)) * 64 + nr] = ao[j];
    }
    xbar();
  }

  // ---- epilogue: out[127] = h_128 @ w_out^T + b_out ----
  {
    const char* hb = smem + LDS_HB + 0 * 2048 + c * 128;   // (128)&1 == 0
    bf16x8 ha0 = *(const bf16x8_a*)(hb + ((g * 16) ^ swzc));
    bf16x8 ha1 = *(const bf16x8_a*)(hb + ((64 + g * 16) ^ swzc));
    f32x4 ao = f32x4{bias_o, bias_o, bias_o, bias_o};
    ao = __builtin_amdgcn_mfma_f32_16x16x32_bf16(ha0, wo[0], ao, 0, 0, 0);
    ao = __builtin_amdgcn_mfma_f32_16x16x32_bf16(ha1, wo[1], ao, 0, 0, 0);
    #pragma unroll
    for (int j = 0; j < 4; ++j)
      out[((size_t)(b0 + 4 * g + j) * 128 + 127) * 64 + nr] = ao[j];
  }
}

extern "C" void kernel_launch(void* const* d_in, const int* in_sizes, int n_in,
                              void* d_out, int out_size, void* d_ws, size_t ws_size,
                              hipStream_t stream) {
  const float* s0    = (const float*)d_in[0];
  const float* a     = (const float*)d_in[1];
  const float* w_ih  = (const float*)d_in[2];
  const float* w_hh  = (const float*)d_in[3];
  const float* b_ih  = (const float*)d_in[4];
  const float* b_hh  = (const float*)d_in[5];
  const float* w_out = (const float*)d_in[6];
  const float* b_out = (const float*)d_in[7];
  float* out = (float*)d_out;
  hipLaunchKernelGGL(gru_fused, dim3(4096 / 16), dim3(256), 0, stream,
                     s0, a, w_ih, w_hh, b_ih, b_hh, w_out, b_out, out);
}

// Round 4
// 77.925 us; speedup vs baseline: 4.1172x; 1.1693x over previous
//
#include <hip/hip_runtime.h>
#include <hip/hip_bf16.h>

typedef __attribute__((ext_vector_type(8))) short bf16x8;   // MFMA A/B frag (4 VGPR)
typedef __attribute__((ext_vector_type(4))) float f32x4;    // MFMA C/D frag
typedef __attribute__((ext_vector_type(2))) float f32x2;

// may_alias everywhere for LDS + vector global loads (R1 lesson: TBAA DSE'd
// init stores -> stale-LDS divergence on graph replays).
typedef bf16x8 bf16x8_a __attribute__((may_alias));
typedef f32x4  f32x4_a  __attribute__((may_alias));
typedef f32x2  f32x2_a  __attribute__((may_alias));
typedef unsigned short u16a __attribute__((may_alias));
typedef unsigned int u32;

// R4: raw HW transcendentals. exp2f without fast-math goes through
// __ocml_exp2_f32 (~12-15 instrs); v_exp_f32 is the 1-ulp HW op and the
// output threshold (1.46e-2) dwarfs its error. Tails saturate correctly
// (exp2(-inf)=0, rcp(inf)=0) so sigmoid/tanh stay exact at extremes.
__device__ __forceinline__ float fexp2(float x) {
  float r; asm("v_exp_f32 %0, %1" : "=v"(r) : "v"(x)); return r;
}
__device__ __forceinline__ float frcp(float x) {
  float r; asm("v_rcp_f32 %0, %1" : "=v"(r) : "v"(x)); return r;
}
__device__ __forceinline__ float sigf(float x) {          // 1/(1+2^(-x*log2e))
  return frcp(1.f + fexp2(x * -1.44269504f));
}
__device__ __forceinline__ float tanhf_(float x) {        // 1 - 2/(1+2^(2x*log2e))
  return 1.f - 2.f * frcp(1.f + fexp2(x * 2.88539008f));
}
// pack two f32 -> two bf16 (RNE) in one HW op
__device__ __forceinline__ u32 cvtpk(float lo, float hi) {
  u32 r; asm("v_cvt_pk_bf16_f32 %0, %1, %2" : "=v"(r) : "v"(lo), "v"(hi)); return r;
}

// LDS: WG = combined weight matrix [192][64] bf16 (rows 0..127: W_s@w_out + W_hh
// for r,z; rows 128..191: W_s@w_out for i_n), swizzled rows of 128 B.
// HB = double-buffered h state [2][16 rows][64 hh] bf16, swizzled.
#define LDS_WG   0        // 192 * 128 = 24576
#define LDS_HB   24576    // 2 * 16 * 128 = 4096
#define LDS_SIZE 28672

__device__ __forceinline__ void stbf(char* smem, int byteoff, float v) {
  union { __hip_bfloat16 b; unsigned short u; } cv;
  cv.b = __float2bfloat16(v);
  *(u16a*)(smem + byteoff) = cv.u;
}
__device__ __forceinline__ void st16(char* smem, int byteoff, unsigned short v) {
  *(u16a*)(smem + byteoff) = v;
}

__device__ __forceinline__ bf16x8 packf8(const float* v) {
  bf16x8 r;
  #pragma unroll
  for (int j = 0; j < 8; ++j) {
    union { __hip_bfloat16 b; short u; } cv;
    cv.b = __float2bfloat16(v[j]);
    r[j] = cv.u;
  }
  return r;
}

// Cross-wave barrier with LDS-only drain: raw s_barrier, lgkmcnt(0) before it.
// Never drains vmcnt -> global out-stores and a-prefetch stay in flight.
__device__ __forceinline__ void xbar() {
  asm volatile("s_waitcnt lgkmcnt(0)\n\ts_barrier" ::: "memory");
}

// grid: 256 blocks x 256 threads (4 waves). Block owns 16 batch rows; wave w
// owns hidden/gate column chunk [16w, 16w+16).
__global__ __launch_bounds__(256, 1)
void gru_fused(const float* __restrict__ s0, const float* __restrict__ a,
               const float* __restrict__ w_ih, const float* __restrict__ w_hh,
               const float* __restrict__ b_ih, const float* __restrict__ b_hh,
               const float* __restrict__ w_out, const float* __restrict__ b_out,
               float* __restrict__ out)
{
  __shared__ __align__(16) char smem[LDS_SIZE];
  const int tid = threadIdx.x;
  const int l = tid & 63;
  const int w = tid >> 6;          // wave id 0..3
  const int c = l & 15;            // MFMA col/row lane
  const int g = l >> 4;            // k-group 0..3
  const int b0 = blockIdx.x * 16;
  const int swzc = (c & 7) << 4;

  // ---- stage s0 -> hbuf[0] (A-frag source for the peeled t=0 step) ----
  for (int idx = tid; idx < 16 * 64; idx += 256) {
    int r = idx >> 6, k = idx & 63;
    stbf(smem, LDS_HB + r * 128 + ((k * 2) ^ ((r & 7) << 4)), s0[(b0 + r) * 64 + k]);
  }

  // ---- prologue: WG = W_s @ w_out (+ W_hh for rows<128), f32-accum MFMA ----
  bf16x8 bwo[4][2];
  #pragma unroll
  for (int i = 0; i < 4; ++i) {
    #pragma unroll
    for (int ks = 0; ks < 2; ++ks) {
      float tv[8];
      #pragma unroll
      for (int j = 0; j < 8; ++j)
        tv[j] = w_out[(ks * 32 + g * 8 + j) * 64 + c + 16 * i];
      bwo[i][ks] = packf8(tv);
    }
  }
  #pragma unroll
  for (int rr = 0; rr < 3; ++rr) {
    int rt = w + 4 * rr;                       // row-tiles 0..11 (n = 16rt..16rt+15)
    bf16x8 wsa[2];                             // A-frag: W_s row 16rt+c, k=dd
    #pragma unroll
    for (int ks = 0; ks < 2; ++ks) {
      float tv[8];
      #pragma unroll
      for (int u = 0; u < 4; ++u) {
        f32x2 t2 = *(const f32x2_a*)(w_ih + (16 * rt + c) * 66 + ks * 32 + g * 8 + 2 * u);
        tv[2 * u] = t2.x; tv[2 * u + 1] = t2.y;
      }
      wsa[ks] = packf8(tv);
    }
    f32x4 acc[4];
    #pragma unroll
    for (int i = 0; i < 4; ++i) {
      #pragma unroll
      for (int j = 0; j < 4; ++j) {
        int n = 16 * rt + 4 * g + j;
        acc[i][j] = (n < 128) ? w_hh[n * 64 + c + 16 * i] : 0.f;
      }
    }
    #pragma unroll
    for (int i = 0; i < 4; ++i)
      #pragma unroll
      for (int ks = 0; ks < 2; ++ks)
        acc[i] = __builtin_amdgcn_mfma_f32_16x16x32_bf16(wsa[ks], bwo[i][ks], acc[i], 0, 0, 0);
    #pragma unroll
    for (int i = 0; i < 4; ++i)
      #pragma unroll
      for (int j = 0; j < 4; ++j) {
        int n = 16 * rt + 4 * g + j;
        stbf(smem, LDS_WG + n * 128 + (((c + 16 * i) * 2) ^ ((n & 7) << 4)), acc[i][j]);
      }
  }

  // ---- per-lane scalars ----
  const int nr = 16 * w + c, nz = 64 + nr, ni = 128 + nr;
  float bs_r = 0.f, bs_z = 0.f, bs_i = 0.f;
  for (int d = 0; d < 64; ++d) {
    float bo = b_out[d];
    bs_r += w_ih[nr * 66 + d] * bo;
    bs_z += w_ih[nz * 66 + d] * bo;
    bs_i += w_ih[ni * 66 + d] * bo;
  }
  const float wa0_r = w_ih[nr * 66 + 64], wa1_r = w_ih[nr * 66 + 65];
  const float wa0_z = w_ih[nz * 66 + 64], wa1_z = w_ih[nz * 66 + 65];
  const float wa0_i = w_ih[ni * 66 + 64], wa1_i = w_ih[ni * 66 + 65];
  const float pb_r = b_ih[nr] + b_hh[nr];          // peel biases (no b_s)
  const float pb_z = b_ih[nz] + b_hh[nz];
  const float pb_i = b_ih[ni];
  const float bias_r = pb_r + bs_r;                // folded biases (with b_s)
  const float bias_z = pb_z + bs_z;
  const float bias_i = pb_i + bs_i;
  const float bias_hn = b_hh[ni];
  const float bias_o = b_out[nr];

  // ---- register B-frags straight from global (row-major row slices) ----
  bf16x8 whn[2], wo[2], wsr[2], wsz[2], wsi[2];
  #pragma unroll
  for (int ks = 0; ks < 2; ++ks) {
    float tv[8];
    f32x4 t4;
    t4 = *(const f32x4_a*)(w_hh + ni * 64 + ks * 32 + g * 8);
    tv[0] = t4.x; tv[1] = t4.y; tv[2] = t4.z; tv[3] = t4.w;
    t4 = *(const f32x4_a*)(w_hh + ni * 64 + ks * 32 + g * 8 + 4);
    tv[4] = t4.x; tv[5] = t4.y; tv[6] = t4.z; tv[7] = t4.w;
    whn[ks] = packf8(tv);
    t4 = *(const f32x4_a*)(w_out + nr * 64 + ks * 32 + g * 8);
    tv[0] = t4.x; tv[1] = t4.y; tv[2] = t4.z; tv[3] = t4.w;
    t4 = *(const f32x4_a*)(w_out + nr * 64 + ks * 32 + g * 8 + 4);
    tv[4] = t4.x; tv[5] = t4.y; tv[6] = t4.z; tv[7] = t4.w;
    wo[ks] = packf8(tv);
    #pragma unroll
    for (int u = 0; u < 4; ++u) {
      f32x2 t2 = *(const f32x2_a*)(w_ih + nr * 66 + ks * 32 + g * 8 + 2 * u);
      tv[2 * u] = t2.x; tv[2 * u + 1] = t2.y;
    }
    wsr[ks] = packf8(tv);
    #pragma unroll
    for (int u = 0; u < 4; ++u) {
      f32x2 t2 = *(const f32x2_a*)(w_ih + nz * 66 + ks * 32 + g * 8 + 2 * u);
      tv[2 * u] = t2.x; tv[2 * u + 1] = t2.y;
    }
    wsz[ks] = packf8(tv);
    #pragma unroll
    for (int u = 0; u < 4; ++u) {
      f32x2 t2 = *(const f32x2_a*)(w_ih + ni * 66 + ks * 32 + g * 8 + 2 * u);
      tv[2 * u] = t2.x; tv[2 * u + 1] = t2.y;
    }
    wsi[ks] = packf8(tv);
  }

  __syncthreads();   // staging + WG writes visible (full drain OK once)

  // WG B-frags from LDS (combined weights)
  bf16x8 wgr[2], wgz[2], wgi[2];
  #pragma unroll
  for (int ks = 0; ks < 2; ++ks) {
    wgr[ks] = *(const bf16x8_a*)(smem + LDS_WG + nr * 128 + ((ks * 64 + g * 16) ^ swzc));
    wgz[ks] = *(const bf16x8_a*)(smem + LDS_WG + nz * 128 + ((ks * 64 + g * 16) ^ swzc));
    wgi[ks] = *(const bf16x8_a*)(smem + LDS_WG + ni * 128 + ((ks * 64 + g * 16) ^ swzc));
  }

  // ---- peeled t=0: gates from explicit s0 (h0 = 0) ----
  bf16x8 sa[2];
  #pragma unroll
  for (int ks = 0; ks < 2; ++ks)
    sa[ks] = *(const bf16x8_a*)(smem + LDS_HB + c * 128 + ((ks * 64 + g * 16) ^ swzc));
  float a0c[4], a1c[4];
  #pragma unroll
  for (int j = 0; j < 4; ++j) {
    f32x2 av = *(const f32x2_a*)(a + (size_t)(b0 + 4 * g + j) * 256);
    a0c[j] = av.x; a1c[j] = av.y;
  }
  f32x4 ar, az, ai;
  #pragma unroll
  for (int j = 0; j < 4; ++j) {
    ar[j] = pb_r + a0c[j] * wa0_r + a1c[j] * wa1_r;
    az[j] = pb_z + a0c[j] * wa0_z + a1c[j] * wa1_z;
    ai[j] = pb_i + a0c[j] * wa0_i + a1c[j] * wa1_i;
  }
  #pragma unroll
  for (int ks = 0; ks < 2; ++ks) {
    ar = __builtin_amdgcn_mfma_f32_16x16x32_bf16(sa[ks], wsr[ks], ar, 0, 0, 0);
    az = __builtin_amdgcn_mfma_f32_16x16x32_bf16(sa[ks], wsz[ks], az, 0, 0, 0);
    ai = __builtin_amdgcn_mfma_f32_16x16x32_bf16(sa[ks], wsi[ks], ai, 0, 0, 0);
  }
  float hreg[4];
  #pragma unroll
  for (int j = 0; j < 4; ++j) {
    float r = sigf(ar[j]);
    float z = sigf(az[j]);
    float nn = tanhf_(ai[j] + r * bias_hn);
    hreg[j] = nn - z * nn;                        // h0 = 0
  }
  {
    u32 p01 = cvtpk(hreg[0], hreg[1]);
    u32 p23 = cvtpk(hreg[2], hreg[3]);
    int r0 = 4 * g;
    st16(smem, LDS_HB + 2048 + (r0    ) * 128 + ((2 * nr) ^ (((r0    ) & 7) << 4)), (unsigned short)(p01));
    st16(smem, LDS_HB + 2048 + (r0 + 1) * 128 + ((2 * nr) ^ (((r0 + 1) & 7) << 4)), (unsigned short)(p01 >> 16));
    st16(smem, LDS_HB + 2048 + (r0 + 2) * 128 + ((2 * nr) ^ (((r0 + 2) & 7) << 4)), (unsigned short)(p23));
    st16(smem, LDS_HB + 2048 + (r0 + 3) * 128 + ((2 * nr) ^ (((r0 + 3) & 7) << 4)), (unsigned short)(p23 >> 16));
  }
  // prefetch a_1
  f32x2 avn[4];
  #pragma unroll
  for (int j = 0; j < 4; ++j)
    avn[j] = *(const f32x2_a*)(a + (size_t)(b0 + 4 * g + j) * 256 + 2);
  xbar();

  // ---- main loop: iteration t reads h_t, emits out[t-1] and h_{t+1} ----
  #pragma unroll 1
  for (int t = 1; t < 128; ++t) {
    const char* hb = smem + LDS_HB + (t & 1) * 2048 + c * 128;
    bf16x8 ha0 = *(const bf16x8_a*)(hb + ((g * 16) ^ swzc));
    bf16x8 ha1 = *(const bf16x8_a*)(hb + ((64 + g * 16) ^ swzc));

    f32x4 ao = f32x4{bias_o, bias_o, bias_o, bias_o};
    ao = __builtin_amdgcn_mfma_f32_16x16x32_bf16(ha0, wo[0], ao, 0, 0, 0);
    ao = __builtin_amdgcn_mfma_f32_16x16x32_bf16(ha1, wo[1], ao, 0, 0, 0);

    #pragma unroll
    for (int j = 0; j < 4; ++j) { a0c[j] = avn[j].x; a1c[j] = avn[j].y; }
    int tn = (t < 127) ? t + 1 : 127;
    #pragma unroll
    for (int j = 0; j < 4; ++j)
      avn[j] = *(const f32x2_a*)(a + (size_t)(b0 + 4 * g + j) * 256 + 2 * tn);

    f32x4 arr, azz, aii, ahh;
    #pragma unroll
    for (int j = 0; j < 4; ++j) {
      arr[j] = bias_r + a0c[j] * wa0_r + a1c[j] * wa1_r;
      azz[j] = bias_z + a0c[j] * wa0_z + a1c[j] * wa1_z;
      aii[j] = bias_i + a0c[j] * wa0_i + a1c[j] * wa1_i;
      ahh[j] = bias_hn;
    }
    arr = __builtin_amdgcn_mfma_f32_16x16x32_bf16(ha0, wgr[0], arr, 0, 0, 0);
    arr = __builtin_amdgcn_mfma_f32_16x16x32_bf16(ha1, wgr[1], arr, 0, 0, 0);
    azz = __builtin_amdgcn_mfma_f32_16x16x32_bf16(ha0, wgz[0], azz, 0, 0, 0);
    azz = __builtin_amdgcn_mfma_f32_16x16x32_bf16(ha1, wgz[1], azz, 0, 0, 0);
    aii = __builtin_amdgcn_mfma_f32_16x16x32_bf16(ha0, wgi[0], aii, 0, 0, 0);
    aii = __builtin_amdgcn_mfma_f32_16x16x32_bf16(ha1, wgi[1], aii, 0, 0, 0);
    ahh = __builtin_amdgcn_mfma_f32_16x16x32_bf16(ha0, whn[0], ahh, 0, 0, 0);
    ahh = __builtin_amdgcn_mfma_f32_16x16x32_bf16(ha1, whn[1], ahh, 0, 0, 0);

    float hv[4];
    #pragma unroll
    for (int j = 0; j < 4; ++j) {
      float r = sigf(arr[j]);
      float z = sigf(azz[j]);
      float nn = tanhf_(aii[j] + r * ahh[j]);
      float h = nn + z * (hreg[j] - nn);
      hv[j] = h;
      hreg[j] = h;
      out[((size_t)(b0 + 4 * g + j) * 128 + (t - 1)) * 64 + nr] = ao[j];
    }
    {
      u32 p01 = cvtpk(hv[0], hv[1]);
      u32 p23 = cvtpk(hv[2], hv[3]);
      int r0 = 4 * g;
      char* hbn = smem + LDS_HB + ((t + 1) & 1) * 2048;
      st16(hbn, (r0    ) * 128 + ((2 * nr) ^ (((r0    ) & 7) << 4)), (unsigned short)(p01));
      st16(hbn, (r0 + 1) * 128 + ((2 * nr) ^ (((r0 + 1) & 7) << 4)), (unsigned short)(p01 >> 16));
      st16(hbn, (r0 + 2) * 128 + ((2 * nr) ^ (((r0 + 2) & 7) << 4)), (unsigned short)(p23));
      st16(hbn, (r0 + 3) * 128 + ((2 * nr) ^ (((r0 + 3) & 7) << 4)), (unsigned short)(p23 >> 16));
    }
    xbar();
  }

  // ---- epilogue: out[127] = h_128 @ w_out^T + b_out ----
  {
    const char* hb = smem + LDS_HB + 0 * 2048 + c * 128;   // (128)&1 == 0
    bf16x8 ha0 = *(const bf16x8_a*)(hb + ((g * 16) ^ swzc));
    bf16x8 ha1 = *(const bf16x8_a*)(hb + ((64 + g * 16) ^ swzc));
    f32x4 ao = f32x4{bias_o, bias_o, bias_o, bias_o};
    ao = __builtin_amdgcn_mfma_f32_16x16x32_bf16(ha0, wo[0], ao, 0, 0, 0);
    ao = __builtin_amdgcn_mfma_f32_16x16x32_bf16(ha1, wo[1], ao, 0, 0, 0);
    #pragma unroll
    for (int j = 0; j < 4; ++j)
      out[((size_t)(b0 + 4 * g + j) * 128 + 127) * 64 + nr] = ao[j];
  }
}

extern "C" void kernel_launch(void* const* d_in, const int* in_sizes, int n_in,
                              void* d_out, int out_size, void* d_ws, size_t ws_size,
                              hipStream_t stream) {
  const float* s0    = (const float*)d_in[0];
  const float* a     = (const float*)d_in[1];
  const float* w_ih  = (const float*)d_in[2];
  const float* w_hh  = (const float*)d_in[3];
  const float* b_ih  = (const float*)d_in[4];
  const float* b_hh  = (const float*)d_in[5];
  const float* w_out = (const float*)d_in[6];
  const float* b_out = (const float*)d_in[7];
  float* out = (float*)d_out;
  hipLaunchKernelGGL(gru_fused, dim3(4096 / 16), dim3(256), 0, stream,
                     s0, a, w_ih, w_hh, b_ih, b_hh, w_out, b_out, out);
}